// Round 1
// baseline (1860.963 us; speedup 1.0000x reference)
//
#include <hip/hip_runtime.h>

#define TT 2048
#define SS 128
#define DMAXX 128
#define NBATCH 64

__device__ __forceinline__ float fexp2(float x){ return __builtin_amdgcn_exp2f(x); }
__device__ __forceinline__ float flog2(float x){ return __builtin_amdgcn_logf(x); }
__device__ __forceinline__ float frcp (float x){ return __builtin_amdgcn_rcpf(x); }

// One workgroup per batch. 512 threads: j = tid>>2 (state), q = tid&3 (lag quarter).
// Thread (j,q) owns ring lags d in [32q+1, 32q+32], expD[j][32q..32q+31], expA[32q..32q+31][j].
__launch_bounds__(512, 2)
__global__ void hsmm_fwd_kernel(const float* __restrict__ logB,
                                const float* __restrict__ pi,
                                const float* __restrict__ A,
                                const float* __restrict__ D,
                                float* __restrict__ out)
{
    constexpr float LOG2E = 1.4426950408889634f;
    constexpr float LN2   = 0.6931471805599453f;
    const int b   = blockIdx.x;
    const int tid = threadIdx.x;
    const int j   = tid >> 2;
    const int q   = tid & 3;

    // U_alpha exchange buffer, chunk layout: chunk c (i in [32c,32c+32)) at [c*36 + (i&31)]
    // stride 36 floats: 16B-aligned chunk bases AND bank-spread across q for b128 reads.
    __shared__ __align__(16) float ua[2][4 * 36];
    __shared__ __align__(16) float wmax[2][8];

    // constant tables in registers
    float eA[32], eD[32];
#pragma unroll
    for (int k = 0; k < 32; ++k) {
        eA[k] = fexp2(A[(q * 32 + k) * SS + j] * LOG2E);   // expA[i][j], i = 32q+k
        eD[k] = fexp2(D[j * DMAXX + q * 32 + k] * LOG2E);  // expD[j][d-1], d-1 = 32q+k
    }
    float r[32];
#pragma unroll
    for (int k = 0; k < 32; ++k) r[k] = 0.f;

    const float* __restrict__ lb = logB + ((size_t)b * TT) * SS + j;

    float C = 0.f;

    // ---------------- step 0 (peeled: entry = pi, inv_m = 1) ----------------
    {
        float eB  = fexp2(lb[0] * LOG2E);
        float etr = fexp2(pi[j] * LOG2E);   // Etrans_raw at t=0
        float g   = eB;
        float carry = __shfl_up(r[31], 1);
        if (q == 0) carry = etr;
        float acc0 = 0.f, acc1 = 0.f;
#pragma unroll
        for (int k = 31; k >= 1; --k) {
            r[k] = r[k - 1] * g;
            if (k & 1) acc1 = fmaf(r[k], eD[k], acc1);
            else       acc0 = fmaf(r[k], eD[k], acc0);
        }
        r[0] = carry * g;
        acc0 = fmaf(r[0], eD[0], acc0);
        float acc = acc0 + acc1;
        acc += __shfl_xor(acc, 1);
        acc += __shfl_xor(acc, 2);          // U_alpha[j] on all quad lanes
        float wm = acc;
        wm = fmaxf(wm, __shfl_xor(wm, 4));
        wm = fmaxf(wm, __shfl_xor(wm, 8));
        wm = fmaxf(wm, __shfl_xor(wm, 16));
        wm = fmaxf(wm, __shfl_xor(wm, 32));
        if (q == 0) ua[0][((j >> 5) * 36) + (j & 31)] = acc;
        if ((tid & 63) == 0) wmax[0][tid >> 6] = wm;
        asm volatile("s_waitcnt lgkmcnt(0)\n\ts_barrier" ::: "memory");
    }

    // register prefetch pipeline for log_B (distance 4); raw s_barrier keeps vmcnt in flight
    float pf[4];
#pragma unroll
    for (int k = 0; k < 4; ++k) pf[k] = lb[(size_t)(1 + k) * SS];

    // ---------------- steps 1 .. T-1 ----------------
#pragma unroll 4
    for (int t = 1; t < TT; ++t) {
        const int pb = (t - 1) & 1;
        const int wb = t & 1;

        // previous step's normalizer (all lanes read same 8 floats -> broadcast)
        float4 w0 = *(const float4*)&wmax[pb][0];
        float4 w1 = *(const float4*)&wmax[pb][4];
        float m = fmaxf(fmaxf(fmaxf(w0.x, w0.y), fmaxf(w0.z, w0.w)),
                        fmaxf(fmaxf(w1.x, w1.y), fmaxf(w1.z, w1.w)));
        C += flog2(m) * LN2;                 // accumulates log m_{t-1}, t-1 in [0, T-2]
        float inv_m = frcp(m);

        // trans: Etrans_raw[j] = sum_i U_alpha_prev[i] * expA[i][j], i in [32q, 32q+32)
        const float4* uap = (const float4*)&ua[pb][q * 36];
        float t0 = 0.f, t1 = 0.f, t2 = 0.f, t3 = 0.f;
#pragma unroll
        for (int kk = 0; kk < 8; ++kk) {
            float4 v = uap[kk];
            t0 = fmaf(v.x, eA[4 * kk + 0], t0);
            t1 = fmaf(v.y, eA[4 * kk + 1], t1);
            t2 = fmaf(v.z, eA[4 * kk + 2], t2);
            t3 = fmaf(v.w, eA[4 * kk + 3], t3);
        }
        float tp = (t0 + t1) + (t2 + t3);
        tp += __shfl_xor(tp, 1);
        tp += __shfl_xor(tp, 2);             // Etrans_raw[j] on all quad lanes

        // emission multiplier for this step; issue prefetch for t+4
        float xB = pf[(t - 1) & 3];
        if (t + 4 < TT) pf[(t - 1) & 3] = lb[(size_t)(t + 4) * SS];
        float g = fexp2(xB * LOG2E) * inv_m;

        // ring shift+scale and duration reduction
        float carry = __shfl_up(r[31], 1);   // old r[31] of lag-neighbor (same j)
        if (q == 0) carry = tp;
        float acc0 = 0.f, acc1 = 0.f;
#pragma unroll
        for (int k = 31; k >= 1; --k) {
            r[k] = r[k - 1] * g;
            if (k & 1) acc1 = fmaf(r[k], eD[k], acc1);
            else       acc0 = fmaf(r[k], eD[k], acc0);
        }
        r[0] = carry * g;
        acc0 = fmaf(r[0], eD[0], acc0);
        float acc = acc0 + acc1;
        acc += __shfl_xor(acc, 1);
        acc += __shfl_xor(acc, 2);           // U_alpha[j]
        float wm = acc;
        wm = fmaxf(wm, __shfl_xor(wm, 4));
        wm = fmaxf(wm, __shfl_xor(wm, 8));
        wm = fmaxf(wm, __shfl_xor(wm, 16));
        wm = fmaxf(wm, __shfl_xor(wm, 32));
        if (q == 0) ua[wb][((j >> 5) * 36) + (j & 31)] = acc;
        if ((tid & 63) == 0) wmax[wb][tid >> 6] = wm;
        asm volatile("s_waitcnt lgkmcnt(0)\n\ts_barrier" ::: "memory");
    }

    // ---------------- epilogue: out[b] = C + log(sum_j U_alpha[T-1][j]) ----------------
    if (tid == 0) {
        float s = 0.f;
        for (int i = 0; i < SS; ++i) s += ua[(TT - 1) & 1][((i >> 5) * 36) + (i & 31)];
        out[b] = C + flog2(s) * LN2;
    }
}

extern "C" void kernel_launch(void* const* d_in, const int* in_sizes, int n_in,
                              void* d_out, int out_size, void* d_ws, size_t ws_size,
                              hipStream_t stream) {
    const float* logB = (const float*)d_in[0];   // (64, 2048, 128) f32
    const float* pi   = (const float*)d_in[1];   // (128,) f32
    const float* A    = (const float*)d_in[2];   // (128, 128) f32
    const float* D    = (const float*)d_in[3];   // (128, 128) f32
    float* out        = (float*)d_out;           // (64,) f32
    hipLaunchKernelGGL(hsmm_fwd_kernel, dim3(NBATCH), dim3(512), 0, stream,
                       logB, pi, A, D, out);
}

// Round 3
// 1590.287 us; speedup vs baseline: 1.1702x; 1.1702x over previous
//
#include <hip/hip_runtime.h>

#define TT 2048
#define SS 128
#define DMAXX 128
#define NBATCH 64

__device__ __forceinline__ float fexp2(float x){ return __builtin_amdgcn_exp2f(x); }
__device__ __forceinline__ float flog2(float x){ return __builtin_amdgcn_logf(x); }
__device__ __forceinline__ float frcp (float x){ return __builtin_amdgcn_rcpf(x); }

// DPP cross-lane move (VALU latency, no LDS). CTRL: quad_perm / row_ror / row_bcast.
template<int CTRL>
__device__ __forceinline__ float dppf(float x) {
    int i = __float_as_int(x);
    return __int_as_float(__builtin_amdgcn_update_dpp(i, i, CTRL, 0xF, 0xF, false));
}
#define DPP_XOR1   0xB1  // quad_perm(1,0,3,2)
#define DPP_XOR2   0x4E  // quad_perm(2,3,0,1)
#define DPP_SHUP1  0x90  // quad_perm(0,0,1,2): lane q gets q-1's value (q=0 keeps own)
#define DPP_ROR4   0x124 // row (16-lane) rotate by 4
#define DPP_ROR8   0x128
#define DPP_BC15   0x142 // lane15 -> lanes 16..31 (per 32-lane half)
#define DPP_BC31   0x143 // lane31 -> lanes 32..63

// One workgroup per batch. 512 threads: j = tid>>2 (state), q = tid&3 (lag quarter).
// Thread (j,q) owns ring lags d in [32q+1, 32q+32], expD[j][32q..], expA[32q..][j].
// Scaled-forward in exp domain: step t multiplies everything by g = eB_t / m_{t-1},
// m_{t-1} = max_j U_{t-1}[j] (1-step-stale feedback — STABLE; the 2-step-stale
// variant is an undamped delay-oscillator and overflows -> NaN, R2 post-mortem).
__launch_bounds__(512, 2)
__global__ void hsmm_fwd_kernel(const float* __restrict__ logB,
                                const float* __restrict__ pi,
                                const float* __restrict__ A,
                                const float* __restrict__ D,
                                float* __restrict__ out)
{
    constexpr float LOG2E = 1.4426950408889634f;
    constexpr float LN2   = 0.6931471805599453f;
    const int b   = blockIdx.x;
    const int tid = threadIdx.x;
    const int j   = tid >> 2;
    const int q   = tid & 3;

    // chunk c (i in [32c,32c+32)) at [c*36 + (i&31)]; stride 36 -> 16B-aligned,
    // the 4 q-chunks hit disjoint bank groups on float4 reads (0 conflicts, R1).
    __shared__ __align__(16) float ua[2][4 * 36];
    __shared__ __align__(16) float wmax[2][8];

    float eA[32], eD[32];
#pragma unroll
    for (int k = 0; k < 32; ++k) {
        eA[k] = fexp2(A[(q * 32 + k) * SS + j] * LOG2E);   // expA[i][j], i = 32q+k
        eD[k] = fexp2(D[j * DMAXX + q * 32 + k] * LOG2E);  // expD[j][d-1], d-1 = 32q+k
    }
    float r[32];
#pragma unroll
    for (int k = 0; k < 32; ++k) r[k] = 0.f;

    const float* __restrict__ lb = logB + ((size_t)b * TT) * SS + j;
    float C = 0.f;

    // ---------------- step 0 (entry = pi, g = eB_0) ----------------
    {
        float g   = fexp2(lb[0] * LOG2E);
        float etr = fexp2(pi[j] * LOG2E);
        float carry = (q == 0) ? etr : 0.f;    // all ring slots are zero
        r[0] = carry * g;
        float acc = r[0] * eD[0];
        acc += dppf<DPP_XOR1>(acc);
        acc += dppf<DPP_XOR2>(acc);            // U_0[j], quad-uniform
        if (q == 0) ua[0][((j >> 5) * 36) + (j & 31)] = acc;
        float wm = acc;
        wm = fmaxf(wm, dppf<DPP_ROR4>(wm));
        wm = fmaxf(wm, dppf<DPP_ROR8>(wm));    // row(16) max in all row lanes
        wm = fmaxf(wm, dppf<DPP_BC15>(wm));
        wm = fmaxf(wm, dppf<DPP_BC31>(wm));    // lane63 = wave max
        if ((tid & 63) == 63) wmax[0][tid >> 6] = wm;
        asm volatile("s_waitcnt lgkmcnt(0)\n\ts_barrier" ::: "memory");
    }

    // register prefetch pipeline for log_B (distance 4)
    float pf[4];
#pragma unroll
    for (int k = 0; k < 4; ++k) pf[k] = lb[(size_t)(1 + k) * SS];

    // ---------------- steps 1 .. T-1 ----------------
#pragma unroll 4
    for (int t = 1; t < TT; ++t) {
        const int pb = (t - 1) & 1;
        const int wb = t & 1;

        // issue LDS reads first; wmax+rcp path hides under ua+trans path
        float4 w0 = *(const float4*)&wmax[pb][0];
        float4 w1 = *(const float4*)&wmax[pb][4];
        const float4* uap = (const float4*)&ua[pb][q * 36];

        // normalizer m = max_j U_{t-1}[j]  (1-step stale -> stable, exact)
        float m = fmaxf(fmaxf(fmaxf(w0.x, w0.y), fmaxf(w0.z, w0.w)),
                        fmaxf(fmaxf(w1.x, w1.y), fmaxf(w1.z, w1.w)));
        C += flog2(m) * LN2;
        float inv_m = frcp(m);

        // emission multiplier; keep prefetch 4 ahead
        float xB = pf[(t - 1) & 3];            // logB[t]
        if (t + 4 < TT) pf[(t - 1) & 3] = lb[(size_t)(t + 4) * SS];
        float g = fexp2(xB * LOG2E) * inv_m;   // rescales ring AND inserted tp

        // trans: Etrans[j] = sum_i U_prev[i] * expA[i][j], i in [32q, 32q+32)
        float t0 = 0.f, t1 = 0.f, t2 = 0.f, t3 = 0.f;
#pragma unroll
        for (int kk = 0; kk < 8; ++kk) {
            float4 v = uap[kk];
            t0 = fmaf(v.x, eA[4 * kk + 0], t0);
            t1 = fmaf(v.y, eA[4 * kk + 1], t1);
            t2 = fmaf(v.z, eA[4 * kk + 2], t2);
            t3 = fmaf(v.w, eA[4 * kk + 3], t3);
        }
        float tp = (t0 + t1) + (t2 + t3);
        tp += dppf<DPP_XOR1>(tp);
        tp += dppf<DPP_XOR2>(tp);              // quad-uniform Etrans[j]

        // ring shift+scale and duration reduction (identical math to passing R1)
        float carry = dppf<DPP_SHUP1>(r[31]);  // lag-neighbor's r[31] (same j)
        if (q == 0) carry = tp;
        float acc0 = 0.f, acc1 = 0.f;
#pragma unroll
        for (int k = 31; k >= 1; --k) {
            r[k] = r[k - 1] * g;
            if (k & 1) acc1 = fmaf(r[k], eD[k], acc1);
            else       acc0 = fmaf(r[k], eD[k], acc0);
        }
        r[0] = carry * g;
        acc0 = fmaf(r[0], eD[0], acc0);
        float acc = acc0 + acc1;
        acc += dppf<DPP_XOR1>(acc);
        acc += dppf<DPP_XOR2>(acc);            // U_t[j]
        if (q == 0) ua[wb][((j >> 5) * 36) + (j & 31)] = acc;

        // wave max via DPP; lane63 writes
        float wm = acc;
        wm = fmaxf(wm, dppf<DPP_ROR4>(wm));
        wm = fmaxf(wm, dppf<DPP_ROR8>(wm));
        wm = fmaxf(wm, dppf<DPP_BC15>(wm));
        wm = fmaxf(wm, dppf<DPP_BC31>(wm));
        if ((tid & 63) == 63) wmax[wb][tid >> 6] = wm;

        asm volatile("s_waitcnt lgkmcnt(0)\n\ts_barrier" ::: "memory");
    }

    // ---------------- epilogue ----------------
    if (tid == 0) {
        float s = 0.f;
        for (int i = 0; i < SS; ++i) s += ua[(TT - 1) & 1][((i >> 5) * 36) + (i & 31)];
        out[b] = C + flog2(s) * LN2;
    }
}

extern "C" void kernel_launch(void* const* d_in, const int* in_sizes, int n_in,
                              void* d_out, int out_size, void* d_ws, size_t ws_size,
                              hipStream_t stream) {
    const float* logB = (const float*)d_in[0];   // (64, 2048, 128) f32
    const float* pi   = (const float*)d_in[1];   // (128,) f32
    const float* A    = (const float*)d_in[2];   // (128, 128) f32
    const float* D    = (const float*)d_in[3];   // (128, 128) f32
    float* out        = (float*)d_out;           // (64,) f32
    hipLaunchKernelGGL(hsmm_fwd_kernel, dim3(NBATCH), dim3(512), 0, stream,
                       logB, pi, A, D, out);
}

// Round 4
// 1202.574 us; speedup vs baseline: 1.5475x; 1.3224x over previous
//
#include <hip/hip_runtime.h>

#define TT 2048
#define SS 128
#define DMAXX 128
#define NBATCH 64

typedef float f2 __attribute__((ext_vector_type(2)));

__device__ __forceinline__ float fexp2(float x){ return __builtin_amdgcn_exp2f(x); }
__device__ __forceinline__ float flog2(float x){ return __builtin_amdgcn_logf(x); }
__device__ __forceinline__ float frcp (float x){ return __builtin_amdgcn_rcpf(x); }

// Full-rate packed fp32 (CDNA2+). Default VOP3P modifiers = natural packed math.
__device__ __forceinline__ f2 pk_mul(f2 a, f2 b){
    f2 d; asm("v_pk_mul_f32 %0, %1, %2" : "=v"(d) : "v"(a), "v"(b)); return d;
}
__device__ __forceinline__ f2 pk_fma(f2 a, f2 b, f2 c){
    f2 d; asm("v_pk_fma_f32 %0, %1, %2, %3" : "=v"(d) : "v"(a), "v"(b), "v"(c)); return d;
}

template<int CTRL>
__device__ __forceinline__ float dppf(float x) {
    int i = __float_as_int(x);
    return __int_as_float(__builtin_amdgcn_update_dpp(i, i, CTRL, 0xF, 0xF, false));
}
#define DPP_XOR1   0xB1  // quad_perm(1,0,3,2)
#define DPP_XOR2   0x4E  // quad_perm(2,3,0,1)
#define DPP_SHUP1  0x90  // quad_perm(0,0,1,2): lane q gets q-1's value (q=0 keeps own)
#define DPP_ROR4   0x124
#define DPP_ROR8   0x128
#define DPP_BC15   0x142
#define DPP_BC31   0x143

constexpr float LOG2E = 1.4426950408889634f;
constexpr float LN2   = 0.6931471805599453f;

struct State {
    f2 rp[16];    // ring, register-renamed: at end of step t, reg s holds lag pos p=(s+t+1)&31
    f2 eAp[16];   // (eA[2k], eA[2k+1]),  eA[i] = exp(A[32q+i][j])
    f2 eDe[16];   // (eD[2k], eD[2k+1]),  eD[k] = exp(D[j][32q+k])
    f2 eDo[16];   // (eD[2k+1], eD[(2k+2)&31])  — odd-offset pairs incl. (eD[31],eD[0]) wrap
    float pf[4];  // logB prefetch, distance 4
    float C;      // accumulated log-normalizer
    float e_pi;   // exp(pi[j])
};

template<int PHI>
__device__ __forceinline__ void hsmm_step(State& st, int tb, const float* __restrict__ lb,
                                          float (*ua)[4 * 36], float (*wmax)[8],
                                          int j, int q, int tid)
{
    constexpr int rho = 31 - PHI;        // reg receiving the new datum this step
    constexpr int pb  = (PHI + 1) & 1;   // read side  (== (t-1)&1)
    constexpr int wb  = PHI & 1;         // write side (== t&1)
    const int t = tb + PHI;

    // issue LDS reads first
    float4 w0 = *(const float4*)&wmax[pb][0];
    float4 w1 = *(const float4*)&wmax[pb][4];
    const float4* uap = (const float4*)&ua[pb][q * 36];

    // normalizer m = max_j U_{t-1}[j] (1-step-stale feedback: stable, exact)
    float m = fmaxf(fmaxf(fmaxf(w0.x, w0.y), fmaxf(w0.z, w0.w)),
                    fmaxf(fmaxf(w1.x, w1.y), fmaxf(w1.z, w1.w)));
    st.C += flog2(m) * LN2;
    float inv_m = frcp(m);

    // emission multiplier; keep prefetch 4 ahead
    float xB = st.pf[PHI & 3];           // logB[t]
    if (t + 4 < TT) st.pf[PHI & 3] = lb[(size_t)(t + 4) * SS];
    float g = fexp2(xB * LOG2E) * inv_m;

    // trans: Etrans[j] = sum_{i in chunk q} U_prev[i] * eA[i], packed pairs
    f2 pa; pa.x = 0.f; pa.y = 0.f;
    f2 pc; pc.x = 0.f; pc.y = 0.f;
#pragma unroll
    for (int kk = 0; kk < 8; ++kk) {
        float4 v = uap[kk];
        f2 lo; lo.x = v.x; lo.y = v.y;
        f2 hi; hi.x = v.z; hi.y = v.w;
        pa = pk_fma(lo, st.eAp[2 * kk],     pa);
        pc = pk_fma(hi, st.eAp[2 * kk + 1], pc);
    }
    f2 ps = pa + pc;
    float tp = ps.x + ps.y;
    tp += dppf<DPP_XOR1>(tp);
    tp += dppf<DPP_XOR2>(tp);            // quad-uniform Etrans[j]
    if (tb == 0 && PHI == 0) tp = st.e_pi;   // t==0: entry = pi

    // ring: carry out the expiring datum (pre-scale!), scale all in place, insert
    float rold;
    if constexpr (rho & 1) rold = st.rp[rho >> 1].y; else rold = st.rp[rho >> 1].x;
    float carry = dppf<DPP_SHUP1>(rold);     // lag-neighbor's expiring slot (same j)
    if (q == 0) carry = tp;
    f2 gg; gg.x = g; gg.y = g;
#pragma unroll
    for (int m2 = 0; m2 < 16; ++m2) st.rp[m2] = pk_mul(st.rp[m2], gg);
    if constexpr (rho & 1) st.rp[rho >> 1].y = carry * g;
    else                   st.rp[rho >> 1].x = carry * g;

    // duration sum: weight reg s by eD[(s+t+1)&31] — static rotation, parity-selected bank
    f2 qa; qa.x = 0.f; qa.y = 0.f;
    f2 qb; qb.x = 0.f; qb.y = 0.f;
#pragma unroll
    for (int m2 = 0; m2 < 16; ++m2) {
        f2 w;
        if constexpr (PHI & 1) w = st.eDe[(m2 + ((PHI + 1) >> 1)) & 15];
        else                   w = st.eDo[(m2 + (PHI >> 1)) & 15];
        if (m2 & 1) qb = pk_fma(st.rp[m2], w, qb);
        else        qa = pk_fma(st.rp[m2], w, qa);
    }
    f2 qs = qa + qb;
    float acc = qs.x + qs.y;
    acc += dppf<DPP_XOR1>(acc);
    acc += dppf<DPP_XOR2>(acc);          // U_t[j]
    if (q == 0) ua[wb][((j >> 5) * 36) + (j & 31)] = acc;

    // wave max via DPP; lane63 writes
    float wm = acc;
    wm = fmaxf(wm, dppf<DPP_ROR4>(wm));
    wm = fmaxf(wm, dppf<DPP_ROR8>(wm));
    wm = fmaxf(wm, dppf<DPP_BC15>(wm));
    wm = fmaxf(wm, dppf<DPP_BC31>(wm));
    if ((tid & 63) == 63) wmax[wb][tid >> 6] = wm;

    asm volatile("s_waitcnt lgkmcnt(0)\n\ts_barrier" ::: "memory");
}

__launch_bounds__(512, 2)
__global__ void hsmm_fwd_kernel(const float* __restrict__ logB,
                                const float* __restrict__ pi,
                                const float* __restrict__ A,
                                const float* __restrict__ D,
                                float* __restrict__ out)
{
    const int b   = blockIdx.x;
    const int tid = threadIdx.x;
    const int j   = tid >> 2;
    const int q   = tid & 3;

    __shared__ __align__(16) float ua[2][4 * 36];
    __shared__ __align__(16) float wmax[2][8];

    State st;
#pragma unroll
    for (int k = 0; k < 16; ++k) {
        st.eAp[k].x = fexp2(A[(q * 32 + 2 * k)     * SS + j] * LOG2E);
        st.eAp[k].y = fexp2(A[(q * 32 + 2 * k + 1) * SS + j] * LOG2E);
        st.eDe[k].x = fexp2(D[j * DMAXX + q * 32 + 2 * k]     * LOG2E);
        st.eDe[k].y = fexp2(D[j * DMAXX + q * 32 + 2 * k + 1] * LOG2E);
    }
#pragma unroll
    for (int k = 0; k < 16; ++k) {
        st.eDo[k].x = st.eDe[k].y;
        st.eDo[k].y = st.eDe[(k + 1) & 15].x;   // wraps: eDo[15] = (eD[31], eD[0])
    }
#pragma unroll
    for (int k = 0; k < 16; ++k) { st.rp[k].x = 0.f; st.rp[k].y = 0.f; }
    st.C    = 0.f;
    st.e_pi = fexp2(pi[j] * LOG2E);

    const float* __restrict__ lb = logB + ((size_t)b * TT) * SS + j;
#pragma unroll
    for (int k = 0; k < 4; ++k) st.pf[k] = lb[(size_t)k * SS];

    // t=0 reads wmax[1]; make it identity
    if (tid < 8) wmax[1][tid] = 1.0f;
    __syncthreads();

    for (int tb = 0; tb < TT; tb += 32) {
        hsmm_step< 0>(st, tb, lb, ua, wmax, j, q, tid);
        hsmm_step< 1>(st, tb, lb, ua, wmax, j, q, tid);
        hsmm_step< 2>(st, tb, lb, ua, wmax, j, q, tid);
        hsmm_step< 3>(st, tb, lb, ua, wmax, j, q, tid);
        hsmm_step< 4>(st, tb, lb, ua, wmax, j, q, tid);
        hsmm_step< 5>(st, tb, lb, ua, wmax, j, q, tid);
        hsmm_step< 6>(st, tb, lb, ua, wmax, j, q, tid);
        hsmm_step< 7>(st, tb, lb, ua, wmax, j, q, tid);
        hsmm_step< 8>(st, tb, lb, ua, wmax, j, q, tid);
        hsmm_step< 9>(st, tb, lb, ua, wmax, j, q, tid);
        hsmm_step<10>(st, tb, lb, ua, wmax, j, q, tid);
        hsmm_step<11>(st, tb, lb, ua, wmax, j, q, tid);
        hsmm_step<12>(st, tb, lb, ua, wmax, j, q, tid);
        hsmm_step<13>(st, tb, lb, ua, wmax, j, q, tid);
        hsmm_step<14>(st, tb, lb, ua, wmax, j, q, tid);
        hsmm_step<15>(st, tb, lb, ua, wmax, j, q, tid);
        hsmm_step<16>(st, tb, lb, ua, wmax, j, q, tid);
        hsmm_step<17>(st, tb, lb, ua, wmax, j, q, tid);
        hsmm_step<18>(st, tb, lb, ua, wmax, j, q, tid);
        hsmm_step<19>(st, tb, lb, ua, wmax, j, q, tid);
        hsmm_step<20>(st, tb, lb, ua, wmax, j, q, tid);
        hsmm_step<21>(st, tb, lb, ua, wmax, j, q, tid);
        hsmm_step<22>(st, tb, lb, ua, wmax, j, q, tid);
        hsmm_step<23>(st, tb, lb, ua, wmax, j, q, tid);
        hsmm_step<24>(st, tb, lb, ua, wmax, j, q, tid);
        hsmm_step<25>(st, tb, lb, ua, wmax, j, q, tid);
        hsmm_step<26>(st, tb, lb, ua, wmax, j, q, tid);
        hsmm_step<27>(st, tb, lb, ua, wmax, j, q, tid);
        hsmm_step<28>(st, tb, lb, ua, wmax, j, q, tid);
        hsmm_step<29>(st, tb, lb, ua, wmax, j, q, tid);
        hsmm_step<30>(st, tb, lb, ua, wmax, j, q, tid);
        hsmm_step<31>(st, tb, lb, ua, wmax, j, q, tid);
    }

    // epilogue: out[b] = C + log(sum_j U_{T-1}[j]);  (T-1)&1 == 1
    if (tid == 0) {
        float s = 0.f;
        for (int i = 0; i < SS; ++i) s += ua[1][((i >> 5) * 36) + (i & 31)];
        out[b] = st.C + flog2(s) * LN2;
    }
}

extern "C" void kernel_launch(void* const* d_in, const int* in_sizes, int n_in,
                              void* d_out, int out_size, void* d_ws, size_t ws_size,
                              hipStream_t stream) {
    const float* logB = (const float*)d_in[0];   // (64, 2048, 128) f32
    const float* pi   = (const float*)d_in[1];   // (128,) f32
    const float* A    = (const float*)d_in[2];   // (128, 128) f32
    const float* D    = (const float*)d_in[3];   // (128, 128) f32
    float* out        = (float*)d_out;           // (64,) f32
    hipLaunchKernelGGL(hsmm_fwd_kernel, dim3(NBATCH), dim3(512), 0, stream,
                       logB, pi, A, D, out);
}